// Round 16
// baseline (92.989 us; speedup 1.0000x reference)
//
#include <hip/hip_runtime.h>

#define NROW 8192
#define DIM  128
#define NSEG 16                     // 16 column chunks of 512 cols
#define NBLK (64 * NSEG)            // 1024 Gram blocks
#define BIGF 1e30f

typedef __attribute__((ext_vector_type(8))) short bf16x8;
typedef __attribute__((ext_vector_type(4))) float f32x4;

// ws layout (bytes):
//   [0, 2 MB)            xb2  : bf16, FRAGMENT-MAJOR: group g=row>>4 (512 groups),
//                               chunk c=0..15 (16B), slot row&15 -> every MFMA fragment
//                               load is contiguous 1KB/wave; a 64-col tile = linear 16KB
//   2MB + [0, 32 KB)     sq   : f32 row sq-norms (fp32-exact)
//   2MB + [64, 576 KB)   posS : [NSEG][NROW] f32 partial hardest-pos d^2
//   2MB + [576,1088 KB)  negS : [NSEG][NROW] f32 partial hardest-neg d^2
//
// Session record (dur_us total / tile structure):
//   v0 92.1 LDS-loop | v4 97.6 stream+sort | v5 99.9 2ph128+sort | v6 90.1 2ph64
//   v9 87.9 2ph64+fast-prep (BEST) | v10 92.9 counted-vmcnt | v11 90.8 stream+slim
// Falsified levers: barrier drains, VALU-band, staging path, occupancy 2/3/4 w/SIMD.
// Residual: 42us harness fill + structurally VALU-heavy per-element epilogue.

__device__ __forceinline__ unsigned short f2bf(float f) {
    unsigned u = __float_as_uint(f);
    unsigned r = (u + 0x7fffu + ((u >> 16) & 1u)) >> 16;   // RNE
    return (unsigned short)r;
}

// async global->LDS, 16B per lane; LDS dest wave-uniform base + lane*16
__device__ __forceinline__ void gload_lds16(const void* g, void* l) {
    __builtin_amdgcn_global_load_lds(
        (const __attribute__((address_space(1))) void*)g,
        (__attribute__((address_space(3))) void*)l, 16, 0, 0);
}

// 16 lanes per row, one uint4 store per thread (v9, measured ~2.5-3us).
__global__ __launch_bounds__(256) void prep_kernel(const float* __restrict__ x,
                                                   unsigned short* __restrict__ xb2,
                                                   float* __restrict__ sq,
                                                   float* __restrict__ out) {
    const int t   = threadIdx.x;
    const int row = blockIdx.x * 16 + (t >> 4);
    const int c   = t & 15;                     // 16B chunk of the row
    if (blockIdx.x == 0 && t == 0) out[0] = 0.0f;
    const float* xr = x + (size_t)row * DIM + c * 8;
    float4 f0 = *(const float4*)xr;
    float4 f1 = *(const float4*)(xr + 4);
    float s = f0.x*f0.x + f0.y*f0.y + f0.z*f0.z + f0.w*f0.w
            + f1.x*f1.x + f1.y*f1.y + f1.z*f1.z + f1.w*f1.w;
    #pragma unroll
    for (int m = 1; m <= 8; m <<= 1) s += __shfl_xor(s, m);   // stays in 16-group
    unsigned w0 = (unsigned)f2bf(f0.x) | ((unsigned)f2bf(f0.y) << 16);
    unsigned w1 = (unsigned)f2bf(f0.z) | ((unsigned)f2bf(f0.w) << 16);
    unsigned w2 = (unsigned)f2bf(f1.x) | ((unsigned)f2bf(f1.y) << 16);
    unsigned w3 = (unsigned)f2bf(f1.z) | ((unsigned)f2bf(f1.w) << 16);
    uint4 v = make_uint4(w0, w1, w2, w3);
    *(uint4*)(xb2 + (size_t)(row >> 4) * 2048 + c * 128 + (row & 15) * 8) = v;
    if (c == 0) sq[row] = s;
}

// v9 tile (measured best: 87.90 total) + the only strictly-work-removing tweak
// left: hasDiag hoisted out of the per-element epilogue — 960/1024 blocks drop
// the self-compare (~15% of the per-element VALU chain), exact by construction.
__global__ __launch_bounds__(256, 3) void tile_mfma(const unsigned short* __restrict__ xb2,
                                                    const int* __restrict__ lbl,
                                                    const float* __restrict__ sq,
                                                    float* __restrict__ posS,
                                                    float* __restrict__ negS) {
    __shared__ unsigned short Bs[2][64 * DIM];   // 2 x 16 KB
    const int bid = blockIdx.x;
    const int rb  = bid >> 4;         // 0..63
    const int jq  = bid & 15;         // 0..15
    const int i0  = rb * 128;
    const int jbase = jq * 512;
    const int t    = threadIdx.x;
    const int lane = t & 63;
    const int w    = t >> 6;
    const int wr0  = i0 + w * 32;     // this wave's first row
    const int quad = lane >> 4;
    const int l15  = lane & 15;

    const char* xbB = (const char*)xb2;

    // ---- A fragments: 8 contiguous-1KB loads, once per block ----
    bf16x8 af[2][4];
    const int gA = wr0 >> 4;
    #pragma unroll
    for (int ti = 0; ti < 2; ti++)
        #pragma unroll
        for (int ks = 0; ks < 4; ks++)
            af[ti][ks] = *(const bf16x8*)(xb2 + (size_t)(gA + ti) * 2048 + (ks * 4 + quad) * 128 + l15 * 8);

    // per-lane row metadata
    int lbli[2][4];
    #pragma unroll
    for (int ti = 0; ti < 2; ti++) {
        int4 l4 = *(const int4*)(lbl + wr0 + ti * 16 + quad * 4);
        lbli[ti][0] = l4.x; lbli[ti][1] = l4.y; lbli[ti][2] = l4.z; lbli[ti][3] = l4.w;
    }
    // does this block's row range intersect its col range? (1 of 16 blocks per rb)
    const bool hasDiag = (i0 >= jbase) && (i0 < jbase + 512);

    float posm[2][4], negm[2][4];
    #pragma unroll
    for (int ti = 0; ti < 2; ti++)
        #pragma unroll
        for (int r = 0; r < 4; r++) { posm[ti][r] = -BIGF; negm[ti][r] = BIGF; }

    // ---- prologue: stage B tile jt=0 (linear 16KB copy) ----
    {
        const char* src = xbB + (size_t)(jbase >> 4) * 4096;
        #pragma unroll
        for (int i = 0; i < 4; i++)
            gload_lds16(src + i * 4096 + t * 16, (char*)&Bs[0][0] + i * 4096 + w * 1024);
    }
    __syncthreads();

    #pragma unroll 1
    for (int jt = 0; jt < 8; jt++) {
        const int cur = jt & 1;
        const int j0  = jbase + jt * 64;

        // prefetch next tile (latency hides under this jt's compute)
        if (jt < 7) {
            const char* src = xbB + (size_t)((j0 + 64) >> 4) * 4096;
            #pragma unroll
            for (int i = 0; i < 4; i++)
                gload_lds16(src + i * 4096 + t * 16, (char*)&Bs[cur ^ 1][0] + i * 4096 + w * 1024);
        }

        float sqj[4]; int lblj[4];
        #pragma unroll
        for (int tj = 0; tj < 4; tj++) {
            int c = j0 + tj * 16 + l15;
            sqj[tj]  = sq[c];
            lblj[tj] = lbl[c];
        }

        f32x4 acc[2][4];
        #pragma unroll
        for (int ti = 0; ti < 2; ti++)
            #pragma unroll
            for (int tj = 0; tj < 4; tj++) acc[ti][tj] = (f32x4){0.f, 0.f, 0.f, 0.f};

        #pragma unroll
        for (int ks = 0; ks < 4; ks++) {
            bf16x8 bfr[4];
            #pragma unroll
            for (int tj = 0; tj < 4; tj++)
                bfr[tj] = *(const bf16x8*)((const char*)&Bs[cur][0] + tj * 4096 + (ks * 4 + quad) * 256 + l15 * 16);
            #pragma unroll
            for (int ti = 0; ti < 2; ti++)
                #pragma unroll
                for (int tj = 0; tj < 4; tj++)
                    acc[ti][tj] = __builtin_amdgcn_mfma_f32_16x16x32_bf16(af[ti][ks], bfr[tj], acc[ti][tj], 0, 0, 0);
        }

        // epilogue: diag branch hoisted (block-uniform; exact)
        if (hasDiag) {
            #pragma unroll
            for (int ti = 0; ti < 2; ti++) {
                const int rowg = wr0 + ti * 16 + quad * 4;
                #pragma unroll
                for (int tj = 0; tj < 4; tj++) {
                    const int jc = j0 + tj * 16 + l15;
                    #pragma unroll
                    for (int r = 0; r < 4; r++) {
                        float sr = fmaf(-2.0f, acc[ti][tj][r], sqj[tj]);
                        bool same = (lbli[ti][r] == lblj[tj]);
                        bool self = (jc == rowg + r);
                        posm[ti][r] = fmaxf(posm[ti][r], (same && !self) ? sr : -BIGF);
                        negm[ti][r] = fminf(negm[ti][r], same ? BIGF : sr);
                    }
                }
            }
        } else {
            #pragma unroll
            for (int ti = 0; ti < 2; ti++)
                #pragma unroll
                for (int tj = 0; tj < 4; tj++)
                    #pragma unroll
                    for (int r = 0; r < 4; r++) {
                        float sr = fmaf(-2.0f, acc[ti][tj][r], sqj[tj]);
                        bool same = (lbli[ti][r] == lblj[tj]);
                        posm[ti][r] = fmaxf(posm[ti][r], same ? sr : -BIGF);
                        negm[ti][r] = fminf(negm[ti][r], same ? BIGF : sr);
                    }
        }

        __syncthreads();   // prefetch drained (covered by compute) + guards buffer reuse
    }

    // ---- flush: reduce across the 16 col-lanes, plain store per seg ----
    #pragma unroll
    for (int ti = 0; ti < 2; ti++)
        #pragma unroll
        for (int r = 0; r < 4; r++) {
            float p = posm[ti][r];
            float n = negm[ti][r];
            #pragma unroll
            for (int m = 8; m >= 1; m >>= 1) {
                p = fmaxf(p, __shfl_xor(p, m));
                n = fminf(n, __shfl_xor(n, m));
            }
            if (l15 == 0) {
                int row = wr0 + ti * 16 + quad * 4 + r;
                float sqi = sq[row];
                posS[jq * NROW + row] = fmaxf(0.0f, sqi + p);   // -BIG -> 0 (no positive here)
                negS[jq * NROW + row] = fmaxf(0.0f, sqi + n);   // clamp bf16-noise negatives
            }
        }
}

__global__ __launch_bounds__(256) void tri_final(const float* __restrict__ posS,
                                                 const float* __restrict__ negS,
                                                 const float* __restrict__ margin,
                                                 float* __restrict__ out) {
    int r = blockIdx.x * 256 + threadIdx.x;
    float p = 0.0f, n = BIGF;
    #pragma unroll
    for (int q = 0; q < NSEG; q++) {
        p = fmaxf(p, posS[q * NROW + r]);
        n = fminf(n, negS[q * NROW + r]);
    }
    float m = margin[0];
    float loss = fmaxf(sqrtf(p) - sqrtf(n) + m, 0.0f) * (1.0f / (float)NROW);
    #pragma unroll
    for (int o = 32; o > 0; o >>= 1) loss += __shfl_down(loss, o);
    __shared__ float wsum[4];
    int lane = threadIdx.x & 63, wv = threadIdx.x >> 6;
    if (lane == 0) wsum[wv] = loss;
    __syncthreads();
    if (threadIdx.x == 0) atomicAdd(out, wsum[0] + wsum[1] + wsum[2] + wsum[3]);
}

extern "C" void kernel_launch(void* const* d_in, const int* in_sizes, int n_in,
                              void* d_out, int out_size, void* d_ws, size_t ws_size,
                              hipStream_t stream) {
    const float* x      = (const float*)d_in[0];
    const int*   lbl    = (const int*)d_in[1];
    const float* margin = (const float*)d_in[2];
    float* out = (float*)d_out;

    char* ws = (char*)d_ws;
    unsigned short* xb2 = (unsigned short*)ws;
    float* sq   = (float*)(ws + (2u << 20));
    float* posS = (float*)(ws + (2u << 20) + (64u << 10));
    float* negS = (float*)(ws + (2u << 20) + (576u << 10));

    prep_kernel<<<NROW / 16, 256, 0, stream>>>(x, xb2, sq, out);
    tile_mfma<<<NBLK, 256, 0, stream>>>(xb2, lbl, sq, posS, negS);
    tri_final<<<NROW / 256, 256, 0, stream>>>(posS, negS, margin, out);
}

// Round 17
// 89.646 us; speedup vs baseline: 1.0373x; 1.0373x over previous
//
#include <hip/hip_runtime.h>

#define NROW 8192
#define DIM  128
#define NSEG 16                     // 16 column chunks of 512 cols
#define NBLK (64 * NSEG)            // 1024 Gram blocks
#define BIGF 1e30f

typedef __attribute__((ext_vector_type(8))) short bf16x8;
typedef __attribute__((ext_vector_type(4))) float f32x4;

// ws layout (bytes):
//   [0, 2 MB)            xb2  : bf16, FRAGMENT-MAJOR: group g=row>>4 (512 groups),
//                               chunk c=0..15 (16B), slot row&15 -> every MFMA fragment
//                               load is contiguous 1KB/wave; a 64-col tile = linear 16KB
//   2MB + [0, 32 KB)     sq   : f32 row sq-norms (fp32-exact)
//   2MB + [64, 576 KB)   posS : [NSEG][NROW] f32 partial hardest-pos d^2
//   2MB + [576,1088 KB)  negS : [NSEG][NROW] f32 partial hardest-neg d^2
//
// FINAL session record (dur_us total / tile structure), all bench-measured:
//   v0  92.1  LDS-loop 128x128 + atomics      | v4  97.6  stream + sort
//   v5  99.9  2ph/128 + sort                  | v6  90.1  2ph/64 slim
//   v9  87.9  2ph/64 slim + coalesced prep    <== BEST (this file)
//   v10 92.9  counted-vmcnt 3-buf (T4: hurt)  | v11 90.8  stream + slim (null)
//   v12 93.0  v9 + diag-hoist (code-shape: hurt)
// Falsified levers: barrier vmcnt drains, VALU-count band, staging path,
//   occupancy 2/3/4 w/SIMD, jt unroll-2, epilogue branch duplication.
// Residual budget: 42us harness workspace-fill (fixed) + ~43us tile whose
//   busy content is real (VALU 13 + MFMA 7 + LDS/addr ~6, round-10 PMC) with
//   latency-alternation idle resistant to 4 structural attacks + ~4us prep/final.

__device__ __forceinline__ unsigned short f2bf(float f) {
    unsigned u = __float_as_uint(f);
    unsigned r = (u + 0x7fffu + ((u >> 16) & 1u)) >> 16;   // RNE
    return (unsigned short)r;
}

// async global->LDS, 16B per lane; LDS dest wave-uniform base + lane*16
__device__ __forceinline__ void gload_lds16(const void* g, void* l) {
    __builtin_amdgcn_global_load_lds(
        (const __attribute__((address_space(1))) void*)g,
        (__attribute__((address_space(3))) void*)l, 16, 0, 0);
}

// 16 lanes per row, one uint4 store per thread (measured ~2.5-3us).
__global__ __launch_bounds__(256) void prep_kernel(const float* __restrict__ x,
                                                   unsigned short* __restrict__ xb2,
                                                   float* __restrict__ sq,
                                                   float* __restrict__ out) {
    const int t   = threadIdx.x;
    const int row = blockIdx.x * 16 + (t >> 4);
    const int c   = t & 15;                     // 16B chunk of the row
    if (blockIdx.x == 0 && t == 0) out[0] = 0.0f;
    const float* xr = x + (size_t)row * DIM + c * 8;
    float4 f0 = *(const float4*)xr;
    float4 f1 = *(const float4*)(xr + 4);
    float s = f0.x*f0.x + f0.y*f0.y + f0.z*f0.z + f0.w*f0.w
            + f1.x*f1.x + f1.y*f1.y + f1.z*f1.z + f1.w*f1.w;
    #pragma unroll
    for (int m = 1; m <= 8; m <<= 1) s += __shfl_xor(s, m);   // stays in 16-group
    unsigned w0 = (unsigned)f2bf(f0.x) | ((unsigned)f2bf(f0.y) << 16);
    unsigned w1 = (unsigned)f2bf(f0.z) | ((unsigned)f2bf(f0.w) << 16);
    unsigned w2 = (unsigned)f2bf(f1.x) | ((unsigned)f2bf(f1.y) << 16);
    unsigned w3 = (unsigned)f2bf(f1.z) | ((unsigned)f2bf(f1.w) << 16);
    uint4 v = make_uint4(w0, w1, w2, w3);
    *(uint4*)(xb2 + (size_t)(row >> 4) * 2048 + c * 128 + (row & 15) * 8) = v;
    if (c == 0) sq[row] = s;
}

// v9 tile (measured best): 64 row-panels x 16 col-chunks, 4 waves stacked
// (wave owns 32 rows x 64 cols; acc[2][4]+af[2][4], VGPR=64), B double-buffered
// 2x16KB via linear global_load_lds, prefetch-before-compute, one barrier per
// jt, A frags register-resident, extrema in registers, per-seg plain stores
// (waves own disjoint rows -> no atomics, no races). Single compact epilogue
// (branch duplication measured -5us: code shape beats dynamic op count here).
__global__ __launch_bounds__(256, 3) void tile_mfma(const unsigned short* __restrict__ xb2,
                                                    const int* __restrict__ lbl,
                                                    const float* __restrict__ sq,
                                                    float* __restrict__ posS,
                                                    float* __restrict__ negS) {
    __shared__ unsigned short Bs[2][64 * DIM];   // 2 x 16 KB
    const int bid = blockIdx.x;
    const int rb  = bid >> 4;         // 0..63
    const int jq  = bid & 15;         // 0..15
    const int i0  = rb * 128;
    const int jbase = jq * 512;
    const int t    = threadIdx.x;
    const int lane = t & 63;
    const int w    = t >> 6;
    const int wr0  = i0 + w * 32;     // this wave's first row
    const int quad = lane >> 4;
    const int l15  = lane & 15;

    const char* xbB = (const char*)xb2;

    // ---- A fragments: 8 contiguous-1KB loads, once per block ----
    bf16x8 af[2][4];
    const int gA = wr0 >> 4;
    #pragma unroll
    for (int ti = 0; ti < 2; ti++)
        #pragma unroll
        for (int ks = 0; ks < 4; ks++)
            af[ti][ks] = *(const bf16x8*)(xb2 + (size_t)(gA + ti) * 2048 + (ks * 4 + quad) * 128 + l15 * 8);

    // per-lane row metadata
    int lbli[2][4];
    #pragma unroll
    for (int ti = 0; ti < 2; ti++) {
        int4 l4 = *(const int4*)(lbl + wr0 + ti * 16 + quad * 4);
        lbli[ti][0] = l4.x; lbli[ti][1] = l4.y; lbli[ti][2] = l4.z; lbli[ti][3] = l4.w;
    }
    // does this block's row range intersect its col range? (1 of 16 blocks per rb)
    const bool hasDiag = (i0 >= jbase) && (i0 < jbase + 512);

    float posm[2][4], negm[2][4];
    #pragma unroll
    for (int ti = 0; ti < 2; ti++)
        #pragma unroll
        for (int r = 0; r < 4; r++) { posm[ti][r] = -BIGF; negm[ti][r] = BIGF; }

    // ---- prologue: stage B tile jt=0 (linear 16KB copy) ----
    {
        const char* src = xbB + (size_t)(jbase >> 4) * 4096;
        #pragma unroll
        for (int i = 0; i < 4; i++)
            gload_lds16(src + i * 4096 + t * 16, (char*)&Bs[0][0] + i * 4096 + w * 1024);
    }
    __syncthreads();

    #pragma unroll 1
    for (int jt = 0; jt < 8; jt++) {
        const int cur = jt & 1;
        const int j0  = jbase + jt * 64;

        // prefetch next tile (latency hides under this jt's compute)
        if (jt < 7) {
            const char* src = xbB + (size_t)((j0 + 64) >> 4) * 4096;
            #pragma unroll
            for (int i = 0; i < 4; i++)
                gload_lds16(src + i * 4096 + t * 16, (char*)&Bs[cur ^ 1][0] + i * 4096 + w * 1024);
        }

        float sqj[4]; int lblj[4];
        #pragma unroll
        for (int tj = 0; tj < 4; tj++) {
            int c = j0 + tj * 16 + l15;
            sqj[tj]  = sq[c];
            lblj[tj] = lbl[c];
        }

        f32x4 acc[2][4];
        #pragma unroll
        for (int ti = 0; ti < 2; ti++)
            #pragma unroll
            for (int tj = 0; tj < 4; tj++) acc[ti][tj] = (f32x4){0.f, 0.f, 0.f, 0.f};

        #pragma unroll
        for (int ks = 0; ks < 4; ks++) {
            bf16x8 bfr[4];
            #pragma unroll
            for (int tj = 0; tj < 4; tj++)
                bfr[tj] = *(const bf16x8*)((const char*)&Bs[cur][0] + tj * 4096 + (ks * 4 + quad) * 256 + l15 * 16);
            #pragma unroll
            for (int ti = 0; ti < 2; ti++)
                #pragma unroll
                for (int tj = 0; tj < 4; tj++)
                    acc[ti][tj] = __builtin_amdgcn_mfma_f32_16x16x32_bf16(af[ti][ks], bfr[tj], acc[ti][tj], 0, 0, 0);
        }

        // epilogue: direct label compare (single compact body)
        #pragma unroll
        for (int ti = 0; ti < 2; ti++) {
            const int rowg = wr0 + ti * 16 + quad * 4;
            #pragma unroll
            for (int tj = 0; tj < 4; tj++) {
                const int jc = j0 + tj * 16 + l15;
                #pragma unroll
                for (int r = 0; r < 4; r++) {
                    float sr = fmaf(-2.0f, acc[ti][tj][r], sqj[tj]);
                    bool same = (lbli[ti][r] == lblj[tj]);
                    bool self = hasDiag && (jc == rowg + r);
                    posm[ti][r] = fmaxf(posm[ti][r], (same && !self) ? sr : -BIGF);
                    negm[ti][r] = fminf(negm[ti][r], same ? BIGF : sr);
                }
            }
        }

        __syncthreads();   // prefetch drained (covered by compute) + guards buffer reuse
    }

    // ---- flush: reduce across the 16 col-lanes, plain store per seg ----
    #pragma unroll
    for (int ti = 0; ti < 2; ti++)
        #pragma unroll
        for (int r = 0; r < 4; r++) {
            float p = posm[ti][r];
            float n = negm[ti][r];
            #pragma unroll
            for (int m = 8; m >= 1; m >>= 1) {
                p = fmaxf(p, __shfl_xor(p, m));
                n = fminf(n, __shfl_xor(n, m));
            }
            if (l15 == 0) {
                int row = wr0 + ti * 16 + quad * 4 + r;
                float sqi = sq[row];
                posS[jq * NROW + row] = fmaxf(0.0f, sqi + p);   // -BIG -> 0 (no positive here)
                negS[jq * NROW + row] = fmaxf(0.0f, sqi + n);   // clamp bf16-noise negatives
            }
        }
}

__global__ __launch_bounds__(256) void tri_final(const float* __restrict__ posS,
                                                 const float* __restrict__ negS,
                                                 const float* __restrict__ margin,
                                                 float* __restrict__ out) {
    int r = blockIdx.x * 256 + threadIdx.x;
    float p = 0.0f, n = BIGF;
    #pragma unroll
    for (int q = 0; q < NSEG; q++) {
        p = fmaxf(p, posS[q * NROW + r]);
        n = fminf(n, negS[q * NROW + r]);
    }
    float m = margin[0];
    float loss = fmaxf(sqrtf(p) - sqrtf(n) + m, 0.0f) * (1.0f / (float)NROW);
    #pragma unroll
    for (int o = 32; o > 0; o >>= 1) loss += __shfl_down(loss, o);
    __shared__ float wsum[4];
    int lane = threadIdx.x & 63, wv = threadIdx.x >> 6;
    if (lane == 0) wsum[wv] = loss;
    __syncthreads();
    if (threadIdx.x == 0) atomicAdd(out, wsum[0] + wsum[1] + wsum[2] + wsum[3]);
}

extern "C" void kernel_launch(void* const* d_in, const int* in_sizes, int n_in,
                              void* d_out, int out_size, void* d_ws, size_t ws_size,
                              hipStream_t stream) {
    const float* x      = (const float*)d_in[0];
    const int*   lbl    = (const int*)d_in[1];
    const float* margin = (const float*)d_in[2];
    float* out = (float*)d_out;

    char* ws = (char*)d_ws;
    unsigned short* xb2 = (unsigned short*)ws;
    float* sq   = (float*)(ws + (2u << 20));
    float* posS = (float*)(ws + (2u << 20) + (64u << 10));
    float* negS = (float*)(ws + (2u << 20) + (576u << 10));

    prep_kernel<<<NROW / 16, 256, 0, stream>>>(x, xb2, sq, out);
    tile_mfma<<<NBLK, 256, 0, stream>>>(xb2, lbl, sq, posS, negS);
    tri_final<<<NROW / 256, 256, 0, stream>>>(posS, negS, margin, out);
}